// Round 7
// baseline (78.403 us; speedup 1.0000x reference)
//
#include <hip/hip_runtime.h>
#include <math.h>

#define N 768
#define CS 384
#define CP 128
#define NBIN 65

typedef float f4 __attribute__((ext_vector_type(4)));
typedef float f2 __attribute__((ext_vector_type(2)));

#define NM (N * N)                 // 589824 (n,m) pairs
#define TOTAL_F4 (NM * (CP / 4))   // 18,874,368 float4 outputs
#define PROJ_BLOCKS (N / 4)        // 192
#define REL_BLOCKS ((NBIN + 1) / 2)  // 33
#define DM_BLOCKS (NM / 256)       // 2304

// Fused prep: [0,192) projections; [192,225) rel table; [225,2529) dm table.
__global__ __launch_bounds__(256) void prep_kernel(
    const float* __restrict__ s,
    const float* __restrict__ Wi, const float* __restrict__ bi,
    const float* __restrict__ Wj, const float* __restrict__ bj,
    const float* __restrict__ Wrel, const float* __restrict__ brel,
    const float* __restrict__ bt,
    const float* __restrict__ trans, const float* __restrict__ mask,
    float* __restrict__ pI, float* __restrict__ pJ, float* __restrict__ relT,
    f2* __restrict__ dm2) {
  const int tid = threadIdx.x;

  if (blockIdx.x >= PROJ_BLOCKS + REL_BLOCKS) {
    // dm table: dm2[n*N+m] = {dist(n,m), mask[n][m]}
    const int e = (blockIdx.x - (PROJ_BLOCKS + REL_BLOCKS)) * 256 + tid;
    const unsigned nn = (unsigned)e / N;
    const unsigned mm = (unsigned)e - nn * N;
    const float dx = trans[nn * 3 + 0] - trans[mm * 3 + 0];
    const float dy = trans[nn * 3 + 1] - trans[mm * 3 + 1];
    const float dz = trans[nn * 3 + 2] - trans[mm * 3 + 2];
    f2 dm;
    dm.x = sqrtf(1e-10f + dx * dx + dy * dy + dz * dz);
    dm.y = mask[e];
    dm2[e] = dm;
    return;
  }

  if (blockIdx.x >= PROJ_BLOCKS) {
    const int bb = (blockIdx.x - PROJ_BLOCKS) * 2 + (tid >> 7);
    const int p = tid & 127;
    if (bb < NBIN)
      relT[bb * CP + p] = Wrel[p * NBIN + bb] + brel[p] + bt[p];
    return;
  }

  __shared__ float s_sh[4 * CS];
  const int n0 = blockIdx.x * 4;
  for (int i = tid; i < 4 * CS / 4; i += 256)
    reinterpret_cast<f4*>(s_sh)[i] = reinterpret_cast<const f4*>(s + n0 * CS)[i];
  __syncthreads();

  const int which = tid >> 7;   // 0 -> i projection, 1 -> j projection
  const int p = tid & 127;
  const float* W = which ? Wj : Wi;
  const float b = which ? bj[p] : bi[p];
  const f4* W4 = reinterpret_cast<const f4*>(W + p * CS);
  const f4* S4 = reinterpret_cast<const f4*>(s_sh);

  float acc0 = b, acc1 = b, acc2 = b, acc3 = b;
  for (int c4 = 0; c4 < CS / 4; ++c4) {
    const f4 w = W4[c4];
    const f4 s0 = S4[0 * (CS / 4) + c4];
    const f4 s1 = S4[1 * (CS / 4) + c4];
    const f4 s2 = S4[2 * (CS / 4) + c4];
    const f4 s3 = S4[3 * (CS / 4) + c4];
    acc0 += s0.x * w.x + s0.y * w.y + s0.z * w.z + s0.w * w.w;
    acc1 += s1.x * w.x + s1.y * w.y + s1.z * w.z + s1.w * w.w;
    acc2 += s2.x * w.x + s2.y * w.y + s2.z * w.z + s2.w * w.w;
    acc3 += s3.x * w.x + s3.y * w.y + s3.z * w.z + s3.w * w.w;
  }
  float* outp = which ? pJ : pI;
  outp[(n0 + 0) * CP + p] = acc0;
  outp[(n0 + 1) * CP + p] = acc1;
  outp[(n0 + 2) * CP + p] = acc2;
  outp[(n0 + 3) * CP + p] = acc3;
}

// Pair kernel, fill-style: flat grid-stride over all float4 outputs.
// No LDS, no barrier, minimal VGPR -> store stream shaped exactly like the
// 7 TB/s fillBufferAligned sweep.
__global__ __launch_bounds__(256) void pair_kernel(
    const float* __restrict__ pI, const float* __restrict__ pJ,
    const float* __restrict__ relT, const float* __restrict__ Wt,
    const f2* __restrict__ dm2, float* __restrict__ out) {
  const f4* __restrict__ pI4 = reinterpret_cast<const f4*>(pI);
  const f4* __restrict__ pJ4 = reinterpret_cast<const f4*>(pJ);
  const f4* __restrict__ rel4 = reinterpret_cast<const f4*>(relT);
  f4* __restrict__ out4 = reinterpret_cast<f4*>(out);

  const int stride = gridDim.x * 256;

  for (int idx = blockIdx.x * 256 + threadIdx.x; idx < TOTAL_F4; idx += stride) {
    const unsigned v = (unsigned)idx & 31u;        // float4 index in channel dim
    const unsigned nm = (unsigned)idx >> 5;        // n*N + m
    const unsigned n = nm / N;                     // magic-mul division
    const unsigned m = nm - n * N;

    int d = (int)n - (int)m;
    d = d < -32 ? -32 : (d > 32 ? 32 : d);

    const f4 pi4 = pI4[n * (CP / 4) + v];
    const f4 pj4 = pJ4[m * (CP / 4) + v];
    const f4 rl = rel4[(unsigned)(d + 32) * (CP / 4) + v];
    const f4 wt4 = reinterpret_cast<const f4*>(Wt)[v];
    const f2 dm = dm2[nm];

    const f4 o = (pi4 + pj4 + rl + dm.x * wt4) * dm.y;
    out4[idx] = o;
  }
}

extern "C" void kernel_launch(void* const* d_in, const int* in_sizes, int n_in,
                              void* d_out, int out_size, void* d_ws, size_t ws_size,
                              hipStream_t stream) {
  const float* s      = (const float*)d_in[0];
  const float* trans  = (const float*)d_in[1];
  const float* p_mask = (const float*)d_in[2];
  const float* Wi     = (const float*)d_in[3];
  const float* bi     = (const float*)d_in[4];
  const float* Wj     = (const float*)d_in[5];
  const float* bj     = (const float*)d_in[6];
  const float* Wrel   = (const float*)d_in[7];
  const float* brel   = (const float*)d_in[8];
  const float* Wt     = (const float*)d_in[9];
  const float* bt     = (const float*)d_in[10];
  float* out = (float*)d_out;

  float* ws   = (float*)d_ws;
  float* pI   = ws;                         // N*CP floats
  float* pJ   = ws + N * CP;                // N*CP floats
  float* relT = ws + 2 * N * CP;            // NBIN*CP floats (8320)
  f2*   dm2   = reinterpret_cast<f2*>(ws + 2 * N * CP + NBIN * CP);  // NM f2

  prep_kernel<<<PROJ_BLOCKS + REL_BLOCKS + DM_BLOCKS, 256, 0, stream>>>(
      s, Wi, bi, Wj, bj, Wrel, brel, bt, trans, p_mask, pI, pJ, relT, dm2);
  pair_kernel<<<2048, 256, 0, stream>>>(pI, pJ, relT, Wt, dm2, out);
}

// Round 9
// 70.812 us; speedup vs baseline: 1.1072x; 1.1072x over previous
//
#include <hip/hip_runtime.h>
#include <math.h>

#define N 768
#define CS 384
#define CP 128
#define NBIN 65
#define MT 64    // m-tile per pair-kernel block
#define KH (CS / 2)  // 192: K-split half

typedef float f4 __attribute__((ext_vector_type(4)));
typedef float f2 __attribute__((ext_vector_type(2)));

#define PROJ_BLOCKS (N / 4)            // 192 (4 rows each)
#define REL_BLOCKS ((NBIN + 3) / 4)    // 17 (4 bins each)

// Prep, latency-optimized: 512-thread blocks.
// Proj block (bid < 192): 4 rows; threads = {which:2} x {khalf:2} x {p:128},
// each computes a half-K partial dot for 4 rows; LDS combine.
// Rel block: 4 bins x 128 channels.
__global__ __launch_bounds__(512) void prep_kernel(
    const float* __restrict__ s,
    const float* __restrict__ Wi, const float* __restrict__ bi,
    const float* __restrict__ Wj, const float* __restrict__ bj,
    const float* __restrict__ Wrel, const float* __restrict__ brel,
    const float* __restrict__ bt,
    float* __restrict__ pI, float* __restrict__ pJ, float* __restrict__ relT) {
  const int tid = threadIdx.x;

  if (blockIdx.x >= PROJ_BLOCKS) {
    const int bb = (blockIdx.x - PROJ_BLOCKS) * 4 + (tid >> 7);
    const int p = tid & 127;
    if (bb < NBIN)
      relT[bb * CP + p] = Wrel[p * NBIN + bb] + brel[p] + bt[p];
    return;
  }

  __shared__ float s_sh[4 * CS];                 // 6 KB
  __shared__ float part_sh[2][2][128][4];        // 8 KB: [which][kh][p][row]

  const int n0 = blockIdx.x * 4;
  if (tid < 4 * CS / 4)
    reinterpret_cast<f4*>(s_sh)[tid] = reinterpret_cast<const f4*>(s + n0 * CS)[tid];
  __syncthreads();

  const int which = tid >> 8;        // 0 -> i, 1 -> j
  const int kh = (tid >> 7) & 1;     // K half
  const int p = tid & 127;
  const float* W = which ? Wj : Wi;
  const f4* W4 = reinterpret_cast<const f4*>(W + p * CS + kh * KH);
  const f4* S4 = reinterpret_cast<const f4*>(s_sh + kh * KH);

  float acc0 = 0.f, acc1 = 0.f, acc2 = 0.f, acc3 = 0.f;
#pragma unroll 8
  for (int c4 = 0; c4 < KH / 4; ++c4) {
    const f4 w = W4[c4];
    const f4 s0 = S4[0 * (CS / 4) + c4];
    const f4 s1 = S4[1 * (CS / 4) + c4];
    const f4 s2 = S4[2 * (CS / 4) + c4];
    const f4 s3 = S4[3 * (CS / 4) + c4];
    acc0 += s0.x * w.x + s0.y * w.y + s0.z * w.z + s0.w * w.w;
    acc1 += s1.x * w.x + s1.y * w.y + s1.z * w.z + s1.w * w.w;
    acc2 += s2.x * w.x + s2.y * w.y + s2.z * w.z + s2.w * w.w;
    acc3 += s3.x * w.x + s3.y * w.y + s3.z * w.z + s3.w * w.w;
  }
  part_sh[which][kh][p][0] = acc0;
  part_sh[which][kh][p][1] = acc1;
  part_sh[which][kh][p][2] = acc2;
  part_sh[which][kh][p][3] = acc3;
  __syncthreads();

  if (tid < 256) {
    const int w2 = tid >> 7;
    const int p2 = tid & 127;
    const float b = w2 ? bj[p2] : bi[p2];
    float* outp = w2 ? pJ : pI;
#pragma unroll
    for (int r = 0; r < 4; ++r)
      outp[(n0 + r) * CP + p2] =
          part_sh[w2][0][p2][r] + part_sh[w2][1][p2][r] + b;
  }
}

// Pair kernel: byte-identical structure to R4 (known 73.4 us).
__global__ __launch_bounds__(256) void pair_kernel(
    const float* __restrict__ pI, const float* __restrict__ pJ,
    const float* __restrict__ relT, const float* __restrict__ Wt,
    const float* __restrict__ trans, const float* __restrict__ mask,
    float* __restrict__ out) {
  __shared__ f2 dm_sh[MT];   // {dist, mask} per m

  const int n = blockIdx.y;
  const int m0 = blockIdx.x * MT;
  const int tid = threadIdx.x;

  if (tid < MT) {
    const int m = m0 + tid;
    const float dx = trans[n * 3 + 0] - trans[m * 3 + 0];
    const float dy = trans[n * 3 + 1] - trans[m * 3 + 1];
    const float dz = trans[n * 3 + 2] - trans[m * 3 + 2];
    f2 dm;
    dm.x = sqrtf(1e-10f + dx * dx + dy * dy + dz * dz);
    dm.y = mask[n * N + m];
    dm_sh[tid] = dm;
  }
  __syncthreads();

  const int v = tid & 31;        // float4 index within 128 channels
  const int slot = tid >> 5;     // 0..7

  const f4 pi4 = reinterpret_cast<const f4*>(pI)[n * (CP / 4) + v];
  const f4 wt4 = reinterpret_cast<const f4*>(Wt)[v];
  const f4* __restrict__ pJ4 = reinterpret_cast<const f4*>(pJ);
  const f4* __restrict__ rel4 = reinterpret_cast<const f4*>(relT);
  f4* __restrict__ out4 = reinterpret_cast<f4*>(out) + ((size_t)n * N + m0) * (CP / 4);

#pragma unroll
  for (int k = 0; k < MT / 8; ++k) {
    const int mi = k * 8 + slot;         // wave's 2 slots -> adjacent m -> 1KB contiguous store
    const int m = m0 + mi;
    int d = n - m;
    d = d < -32 ? -32 : (d > 32 ? 32 : d);

    const f4 pj4 = pJ4[m * (CP / 4) + v];
    const f4 rl = rel4[(d + 32) * (CP / 4) + v];
    const f2 dm = dm_sh[mi];

    f4 o;
    o.x = (pi4.x + pj4.x + rl.x + dm.x * wt4.x) * dm.y;
    o.y = (pi4.y + pj4.y + rl.y + dm.x * wt4.y) * dm.y;
    o.z = (pi4.z + pj4.z + rl.z + dm.x * wt4.z) * dm.y;
    o.w = (pi4.w + pj4.w + rl.w + dm.x * wt4.w) * dm.y;

    out4[mi * (CP / 4) + v] = o;
  }
}

extern "C" void kernel_launch(void* const* d_in, const int* in_sizes, int n_in,
                              void* d_out, int out_size, void* d_ws, size_t ws_size,
                              hipStream_t stream) {
  const float* s      = (const float*)d_in[0];
  const float* trans  = (const float*)d_in[1];
  const float* p_mask = (const float*)d_in[2];
  const float* Wi     = (const float*)d_in[3];
  const float* bi     = (const float*)d_in[4];
  const float* Wj     = (const float*)d_in[5];
  const float* bj     = (const float*)d_in[6];
  const float* Wrel   = (const float*)d_in[7];
  const float* brel   = (const float*)d_in[8];
  const float* Wt     = (const float*)d_in[9];
  const float* bt     = (const float*)d_in[10];
  float* out = (float*)d_out;

  float* ws   = (float*)d_ws;
  float* pI   = ws;                 // N*CP floats
  float* pJ   = ws + N * CP;        // N*CP floats
  float* relT = ws + 2 * N * CP;    // NBIN*CP floats

  prep_kernel<<<PROJ_BLOCKS + REL_BLOCKS, 512, 0, stream>>>(
      s, Wi, bi, Wj, bj, Wrel, brel, bt, pI, pJ, relT);
  pair_kernel<<<dim3(N / MT, N), 256, 0, stream>>>(
      pI, pJ, relT, Wt, trans, p_mask, out);
}

// Round 10
// 68.802 us; speedup vs baseline: 1.1396x; 1.0292x over previous
//
#include <hip/hip_runtime.h>
#include <math.h>

#define N 768
#define CS 384
#define CP 128
#define NBIN 65
#define KH (CS / 2)  // 192: K-split half

typedef float f4 __attribute__((ext_vector_type(4)));
typedef float f2 __attribute__((ext_vector_type(2)));

#define PROJ_BLOCKS (N / 4)            // 192 (4 rows each)
#define REL_BLOCKS ((NBIN + 3) / 4)    // 17 (4 bins each)

// Prep (R9 known-good): 512-thread blocks, K-split halves, LDS combine.
__global__ __launch_bounds__(512) void prep_kernel(
    const float* __restrict__ s,
    const float* __restrict__ Wi, const float* __restrict__ bi,
    const float* __restrict__ Wj, const float* __restrict__ bj,
    const float* __restrict__ Wrel, const float* __restrict__ brel,
    const float* __restrict__ bt,
    float* __restrict__ pI, float* __restrict__ pJ, float* __restrict__ relT) {
  const int tid = threadIdx.x;

  if (blockIdx.x >= PROJ_BLOCKS) {
    const int bb = (blockIdx.x - PROJ_BLOCKS) * 4 + (tid >> 7);
    const int p = tid & 127;
    if (bb < NBIN)
      relT[bb * CP + p] = Wrel[p * NBIN + bb] + brel[p] + bt[p];
    return;
  }

  __shared__ float s_sh[4 * CS];                 // 6 KB
  __shared__ float part_sh[2][2][128][4];        // 8 KB: [which][kh][p][row]

  const int n0 = blockIdx.x * 4;
  if (tid < 4 * CS / 4)
    reinterpret_cast<f4*>(s_sh)[tid] = reinterpret_cast<const f4*>(s + n0 * CS)[tid];
  __syncthreads();

  const int which = tid >> 8;        // 0 -> i, 1 -> j
  const int kh = (tid >> 7) & 1;     // K half
  const int p = tid & 127;
  const float* W = which ? Wj : Wi;
  const f4* W4 = reinterpret_cast<const f4*>(W + p * CS + kh * KH);
  const f4* S4 = reinterpret_cast<const f4*>(s_sh + kh * KH);

  float acc0 = 0.f, acc1 = 0.f, acc2 = 0.f, acc3 = 0.f;
#pragma unroll 8
  for (int c4 = 0; c4 < KH / 4; ++c4) {
    const f4 w = W4[c4];
    const f4 s0 = S4[0 * (CS / 4) + c4];
    const f4 s1 = S4[1 * (CS / 4) + c4];
    const f4 s2 = S4[2 * (CS / 4) + c4];
    const f4 s3 = S4[3 * (CS / 4) + c4];
    acc0 += s0.x * w.x + s0.y * w.y + s0.z * w.z + s0.w * w.w;
    acc1 += s1.x * w.x + s1.y * w.y + s1.z * w.z + s1.w * w.w;
    acc2 += s2.x * w.x + s2.y * w.y + s2.z * w.z + s2.w * w.w;
    acc3 += s3.x * w.x + s3.y * w.y + s3.z * w.z + s3.w * w.w;
  }
  part_sh[which][kh][p][0] = acc0;
  part_sh[which][kh][p][1] = acc1;
  part_sh[which][kh][p][2] = acc2;
  part_sh[which][kh][p][3] = acc3;
  __syncthreads();

  if (tid < 256) {
    const int w2 = tid >> 7;
    const int p2 = tid & 127;
    const float b = w2 ? bj[p2] : bi[p2];
    float* outp = w2 ? pJ : pI;
#pragma unroll
    for (int r = 0; r < 4; ++r)
      outp[(n0 + r) * CP + p2] =
          part_sh[w2][0][p2][r] + part_sh[w2][1][p2][r] + b;
  }
}

// Pair kernel, row-sweep: one block per n-row. Each block linearly streams its
// row's 384 KB of contiguous output (fill-shaped long store stream), with dm
// for the whole row staged once in LDS. 768 blocks = 3/CU, 12 waves/CU.
__global__ __launch_bounds__(256) void pair_kernel(
    const float* __restrict__ pI, const float* __restrict__ pJ,
    const float* __restrict__ relT, const float* __restrict__ Wt,
    const float* __restrict__ trans, const float* __restrict__ mask,
    float* __restrict__ out) {
  __shared__ f2 dm_sh[N];   // {dist, mask} for the whole row: 6 KB

  const int n = blockIdx.x;
  const int tid = threadIdx.x;

  const float tx = trans[n * 3 + 0];
  const float ty = trans[n * 3 + 1];
  const float tz = trans[n * 3 + 2];
  for (int m = tid; m < N; m += 256) {
    const float dx = tx - trans[m * 3 + 0];
    const float dy = ty - trans[m * 3 + 1];
    const float dz = tz - trans[m * 3 + 2];
    f2 dm;
    dm.x = sqrtf(1e-10f + dx * dx + dy * dy + dz * dz);
    dm.y = mask[n * N + m];
    dm_sh[m] = dm;
  }
  __syncthreads();

  const int v = tid & 31;        // float4 index within 128 channels
  const int slot = tid >> 5;     // 0..7

  const f4 pi4 = reinterpret_cast<const f4*>(pI)[n * (CP / 4) + v];
  const f4 wt4 = reinterpret_cast<const f4*>(Wt)[v];
  const f4* __restrict__ pJ4 = reinterpret_cast<const f4*>(pJ);
  const f4* __restrict__ rel4 = reinterpret_cast<const f4*>(relT);
  f4* __restrict__ out4 =
      reinterpret_cast<f4*>(out) + (size_t)n * N * (CP / 4);

#pragma unroll 4
  for (int mm = slot; mm < N; mm += 8) {
    int d = n - mm;
    d = d < -32 ? -32 : (d > 32 ? 32 : d);

    const f4 pj4 = pJ4[mm * (CP / 4) + v];
    const f4 rl = rel4[(d + 32) * (CP / 4) + v];
    const f2 dm = dm_sh[mm];

    const f4 o = (pi4 + pj4 + rl + dm.x * wt4) * dm.y;
    out4[mm * (CP / 4) + v] = o;
  }
}

extern "C" void kernel_launch(void* const* d_in, const int* in_sizes, int n_in,
                              void* d_out, int out_size, void* d_ws, size_t ws_size,
                              hipStream_t stream) {
  const float* s      = (const float*)d_in[0];
  const float* trans  = (const float*)d_in[1];
  const float* p_mask = (const float*)d_in[2];
  const float* Wi     = (const float*)d_in[3];
  const float* bi     = (const float*)d_in[4];
  const float* Wj     = (const float*)d_in[5];
  const float* bj     = (const float*)d_in[6];
  const float* Wrel   = (const float*)d_in[7];
  const float* brel   = (const float*)d_in[8];
  const float* Wt     = (const float*)d_in[9];
  const float* bt     = (const float*)d_in[10];
  float* out = (float*)d_out;

  float* ws   = (float*)d_ws;
  float* pI   = ws;                 // N*CP floats
  float* pJ   = ws + N * CP;        // N*CP floats
  float* relT = ws + 2 * N * CP;    // NBIN*CP floats

  prep_kernel<<<PROJ_BLOCKS + REL_BLOCKS, 512, 0, stream>>>(
      s, Wi, bi, Wj, bj, Wrel, brel, bt, pI, pJ, relT);
  pair_kernel<<<N, 256, 0, stream>>>(
      pI, pJ, relT, Wt, trans, p_mask, out);
}